// Round 5
// baseline (200.792 us; speedup 1.0000x reference)
//
#include <hip/hip_runtime.h>

// Aggregation: input [32,16,16,1024] f32 NHWC, weight [32,256,9,256] f32,
// out [32,1024,16,16] f32.
//
// out[n, g*256+cw, l] = sum_q weight[n,cw,q,l] * input[n, hi, wj, c]
//   m  = 9*(cw&3) + q  (wave-uniform);  p = m>>2 ; di = p/3 ; dj = p%3
//   c  = (m&3)*256 + l ;  hi = 4g + (cw>>6) + di - 1 ; wj = ((cw>>2)&15)+dj-1
//   (0 if hi/wj out of [0,16))
//
// Round-4 lesson: batched loads alone (MLP=9) at 4 waves/SIMD didn't move the
// 48us floor; round-0 had 8 waves/SIMD but serial loads. This round combines
// BOTH: float2 granularity halves per-thread arrays (wgt[9]+v[9] = 36 VGPR),
// __launch_bounds__(256,8) forces <=64 VGPR -> 8 waves/SIMD residency cap,
// grid 4096 blocks (16/CU). If the floor still doesn't move, it's an external
// (clock-governor) floor, not a kernel property.

__global__ __launch_bounds__(256, 8)
void Aggregation_33320356282418_kernel(const float* __restrict__ input,
                                       const float* __restrict__ weight,
                                       float* __restrict__ out) {
    // XCD-aware swizzle: XCD x gets work-ids [x*512,(x+1)*512) = 4 consecutive
    // n (4 MB input working set per XCD L2).
    const int b   = blockIdx.x;             // 0..4095
    const int blk = (b & 7) * 512 + (b >> 3);

    const int pr  = blk & 127;              // cw-pair 0..127
    const int n   = blk >> 7;               // 0..31
    const int tid = threadIdx.x;
    const int cwi = tid >> 7;               // 0..1  (128-thread half = 2 waves)
    const int u   = tid & 127;              // float2 unit within the l-row
    const int cw  = pr * 2 + cwi;

    const int hbase = cw >> 6;              // 0..3
    const int w0    = (cw >> 2) & 15;       // 0..15
    const int mb    = 9 * (cw & 3);

    const float2* __restrict__ inp2 =
        (const float2*)(input + (size_t)n * (16 * 16 * 1024));
    const float2* __restrict__ w2 =
        (const float2*)(weight + (size_t)(n * 256 + cw) * (9 * 256));
    float2* __restrict__ o2 =
        (float2*)(out + ((size_t)n * 1024 + cw) * 256);

    // per-q wave-uniform geometry (clamped addresses, validity as {0,1})
    int   base_q[9];    // float2-unit offset for clamped (col, chunk) + u
    int   hoff_q[9];    // hbase + di - 1
    float ws_q[9];      // 0.0 if col OOB else 1.0
#pragma unroll
    for (int q = 0; q < 9; ++q) {
        const int m  = mb + q;
        const int p  = m >> 2;              // 0..8
        const int di = p / 3;
        const int dj = p - 3 * di;
        const int wj = w0 + dj - 1;
        ws_q[q] = ((unsigned)wj < 16u) ? 1.0f : 0.0f;
        const int wjc = min(max(wj, 0), 15);
        hoff_q[q] = hbase + di - 1;
        base_q[q] = wjc * 512 + (m & 3) * 128 + u;
    }

    // ---- all 9 weight loads, one batch (co-issues with g=0 gathers) ----
    float2 wgt[9];
#pragma unroll
    for (int q = 0; q < 9; ++q) wgt[q] = w2[q * 128 + u];

#pragma unroll
    for (int g = 0; g < 4; ++g) {
        // phase A: 9 unconditional gathers (full MLP batch)
        float2 v[9];
#pragma unroll
        for (int q = 0; q < 9; ++q) {
            const int hi  = 4 * g + hoff_q[q];
            const int hic = min(max(hi, 0), 15);
            v[q] = inp2[hic * (16 * 512) + base_q[q]];
        }
        // phase B: masked FMAs
        float2 acc = make_float2(0.f, 0.f);
#pragma unroll
        for (int q = 0; q < 9; ++q) {
            const int   hi = 4 * g + hoff_q[q];
            const float s  = ((unsigned)hi < 16u) ? ws_q[q] : 0.0f;
            acc.x = fmaf(wgt[q].x * s, v[q].x, acc.x);
            acc.y = fmaf(wgt[q].y * s, v[q].y, acc.y);
        }
        o2[g * (256 * 256 / 2) + u] = acc;      // C = g*256 + cw
    }
}

extern "C" void kernel_launch(void* const* d_in, const int* in_sizes, int n_in,
                              void* d_out, int out_size, void* d_ws, size_t ws_size,
                              hipStream_t stream) {
    const float* input  = (const float*)d_in[0];   // [32,16,16,1024]
    const float* weight = (const float*)d_in[1];   // [32,256,9,256]
    float* out = (float*)d_out;                    // [32,1024,16,16]

    dim3 grid(32 * 128);   // (n, cw-pair)
    dim3 block(256);       // 2 cw x 128 threads (2 waves each)
    hipLaunchKernelGGL(Aggregation_33320356282418_kernel, grid, block, 0, stream,
                       input, weight, out);
}

// Round 7
// 151.877 us; speedup vs baseline: 1.3221x; 1.3221x over previous
//
#include <hip/hip_runtime.h>

// Aggregation: input [32,16,16,1024] f32 NHWC, weight [32,256,9,256] f32,
// out [32,1024,16,16] f32.
//
// out[n, g*256+cw, l] = sum_q weight[n,cw,q,l] * input[n, hi, wj, c]
//   m  = 9*(cw&3) + q  (wave-uniform);  p = m>>2 ; di = p/3 ; dj = p%3
//   c  = (m&3)*256 + l ;  hi = 4g + (cw>>6) + di - 1 ; wj = ((cw>>2)&15)+dj-1
//   (0 if hi/wj out of [0,16))
//
// Round-5 lesson: __launch_bounds__(256,8) forced spills (VGPR=32, WRITE 140MB)
// -> 2x regression. Reverted. Round-4 lesson: 5 serialized load batches/wave
// (v[9] reused per g => WAR) leaves the kernel latency-bound at ~48us with all
// pipes idle. This round: ONE round trip per wave — v[4][9]+wgt[9] all live
// (~220 VGPR, launch_bounds(256,2) gives the 256-VGPR budget), all 45 float4
// loads issued as a single batch, then 144 masked FMAs + 4 stores.

__global__ __launch_bounds__(256, 2)
void Aggregation_33320356282418_kernel(const float* __restrict__ input,
                                       const float* __restrict__ weight,
                                       float* __restrict__ out) {
    // XCD-aware swizzle (2048 blocks = 8*256): XCD x works on 4 consecutive n
    // -> 4 MB input working set per XCD L2.
    const int b   = blockIdx.x;             // 0..2047
    const int blk = (b & 7) * 256 + (b >> 3);

    const int cb  = blk & 63;               // cw-block 0..63
    const int n   = blk >> 6;               // 0..31
    const int tid = threadIdx.x;
    const int cwi = tid >> 6;               // wave id 0..3
    const int t   = tid & 63;               // lane
    const int cw  = cb * 4 + cwi;

    const int hbase = cw >> 6;              // 0..3
    const int w0    = (cw >> 2) & 15;       // 0..15
    const int mb    = 9 * (cw & 3);

    const float4* __restrict__ inp4 =
        (const float4*)(input + (size_t)n * (16 * 16 * 1024));
    const float4* __restrict__ w4 =
        (const float4*)(weight + (size_t)(n * 256 + cw) * (9 * 256));
    float4* __restrict__ o4 =
        (float4*)(out + ((size_t)n * 1024 + cw) * 256);

    // ---- per-q wave-uniform geometry (clamped addresses, validity mask) ----
    int   base_q[9];    // float4-unit offset: clamped col*256 + chunk*64 + t
    int   hoff_q[9];    // hbase + di - 1
    float ws_q[9];      // 0.0 if col OOB else 1.0
#pragma unroll
    for (int q = 0; q < 9; ++q) {
        const int m  = mb + q;
        const int p  = m >> 2;              // 0..8
        const int di = p / 3;
        const int dj = p - 3 * di;
        const int wj = w0 + dj - 1;
        ws_q[q] = ((unsigned)wj < 16u) ? 1.0f : 0.0f;
        const int wjc = min(max(wj, 0), 15);
        hoff_q[q] = hbase + di - 1;
        base_q[q] = wjc * 256 + (m & 3) * 64 + t;
    }

    // ---- ONE load batch: 9 weights + 36 gathers, all independent ----
    float4 wgt[9];
#pragma unroll
    for (int q = 0; q < 9; ++q) wgt[q] = w4[q * 64 + t];

    float4 v[4][9];
#pragma unroll
    for (int g = 0; g < 4; ++g) {
#pragma unroll
        for (int q = 0; q < 9; ++q) {
            const int hi  = 4 * g + hoff_q[q];
            const int hic = min(max(hi, 0), 15);
            v[g][q] = inp4[hic * (16 * 256) + base_q[q]];
        }
    }

    // ---- consume: 144 masked FMAs + 4 stores ----
#pragma unroll
    for (int g = 0; g < 4; ++g) {
        float4 acc = make_float4(0.f, 0.f, 0.f, 0.f);
#pragma unroll
        for (int q = 0; q < 9; ++q) {
            const int   hi = 4 * g + hoff_q[q];
            const float s  = ((unsigned)hi < 16u) ? ws_q[q] : 0.0f;
            acc.x = fmaf(wgt[q].x * s, v[g][q].x, acc.x);
            acc.y = fmaf(wgt[q].y * s, v[g][q].y, acc.y);
            acc.z = fmaf(wgt[q].z * s, v[g][q].z, acc.z);
            acc.w = fmaf(wgt[q].w * s, v[g][q].w, acc.w);
        }
        o4[g * (256 * 256 / 4) + t] = acc;      // C = g*256 + cw
    }
}

extern "C" void kernel_launch(void* const* d_in, const int* in_sizes, int n_in,
                              void* d_out, int out_size, void* d_ws, size_t ws_size,
                              hipStream_t stream) {
    const float* input  = (const float*)d_in[0];   // [32,16,16,1024]
    const float* weight = (const float*)d_in[1];   // [32,256,9,256]
    float* out = (float*)d_out;                    // [32,1024,16,16]

    dim3 grid(32 * 64);    // (n, cw-block-of-4)
    dim3 block(256);       // 4 waves: one cw each
    hipLaunchKernelGGL(Aggregation_33320356282418_kernel, grid, block, 0, stream,
                       input, weight, out);
}

// Round 8
// 150.672 us; speedup vs baseline: 1.3326x; 1.0080x over previous
//
#include <hip/hip_runtime.h>

// Aggregation: input [32,16,16,1024] f32 NHWC, weight [32,256,9,256] f32,
// out [32,1024,16,16] f32.
//
// out[n, g*256+cw, l] = sum_q weight[n,cw,q,l] * input[n, hi, wj, c]
//   m  = 9*(cw&3) + q  (wave-uniform);  p = m>>2 ; di = p/3 ; dj = p%3
//   c  = (m&3)*256 + l ;  hi = 4g + (cw>>6) + di - 1 ; wj = ((cw>>2)&15)+dj-1
//   (0 if hi/wj out of [0,16))
//
// Round-7 lesson: the compiler re-serialized the intended 45-deep load batch
// into ~5 small batches (VGPR=68 instead of ~220). This round pins the batch
// with __builtin_amdgcn_sched_barrier(0): all 45 global_load_dwordx4 must
// issue before any FMA. ~210 VGPR live, launch_bounds(256,2) budget = 256,
// no spill expected (verify via WRITE_SIZE ~32.8MB). This is the final
// discriminating test of the latency-serialization hypothesis vs. the
// environment-floor hypothesis (5 kernels pinned at 48-49us).

__global__ __launch_bounds__(256, 2)
void Aggregation_33320356282418_kernel(const float* __restrict__ input,
                                       const float* __restrict__ weight,
                                       float* __restrict__ out) {
    // XCD-aware swizzle (2048 blocks = 8*256): XCD x works on 4 consecutive n
    // -> 4 MB input working set per XCD L2.
    const int b   = blockIdx.x;             // 0..2047
    const int blk = (b & 7) * 256 + (b >> 3);

    const int cb  = blk & 63;               // cw-block 0..63
    const int n   = blk >> 6;               // 0..31
    const int tid = threadIdx.x;
    const int cwi = tid >> 6;               // wave id 0..3
    const int t   = tid & 63;               // lane
    const int cw  = cb * 4 + cwi;

    const int hbase = cw >> 6;              // 0..3
    const int w0    = (cw >> 2) & 15;       // 0..15
    const int mb    = 9 * (cw & 3);

    const float4* __restrict__ inp4 =
        (const float4*)(input + (size_t)n * (16 * 16 * 1024));
    const float4* __restrict__ w4 =
        (const float4*)(weight + (size_t)(n * 256 + cw) * (9 * 256));
    float4* __restrict__ o4 =
        (float4*)(out + ((size_t)n * 1024 + cw) * 256);

    // ---- per-q wave-uniform geometry (clamped addresses, validity mask) ----
    int   base_q[9];    // float4-unit offset: clamped col*256 + chunk*64 + t
    int   hoff_q[9];    // hbase + di - 1
    float ws_q[9];      // 0.0 if col OOB else 1.0
#pragma unroll
    for (int q = 0; q < 9; ++q) {
        const int m  = mb + q;
        const int p  = m >> 2;              // 0..8
        const int di = p / 3;
        const int dj = p - 3 * di;
        const int wj = w0 + dj - 1;
        ws_q[q] = ((unsigned)wj < 16u) ? 1.0f : 0.0f;
        const int wjc = min(max(wj, 0), 15);
        hoff_q[q] = hbase + di - 1;
        base_q[q] = wjc * 256 + (m & 3) * 64 + t;
    }

    // ---- ONE pinned load batch: 9 weights + 36 gathers ----
    float4 wgt[9];
#pragma unroll
    for (int q = 0; q < 9; ++q) wgt[q] = w4[q * 64 + t];

    float4 v[4][9];
#pragma unroll
    for (int g = 0; g < 4; ++g) {
#pragma unroll
        for (int q = 0; q < 9; ++q) {
            const int hi  = 4 * g + hoff_q[q];
            const int hic = min(max(hi, 0), 15);
            v[g][q] = inp4[hic * (16 * 256) + base_q[q]];
        }
    }

    // Pin the schedule: no FMA may be hoisted above, no load sunk below.
    __builtin_amdgcn_sched_barrier(0);

    // ---- consume: 144 masked FMAs + 4 stores ----
#pragma unroll
    for (int g = 0; g < 4; ++g) {
        float4 acc = make_float4(0.f, 0.f, 0.f, 0.f);
#pragma unroll
        for (int q = 0; q < 9; ++q) {
            const int   hi = 4 * g + hoff_q[q];
            const float s  = ((unsigned)hi < 16u) ? ws_q[q] : 0.0f;
            acc.x = fmaf(wgt[q].x * s, v[g][q].x, acc.x);
            acc.y = fmaf(wgt[q].y * s, v[g][q].y, acc.y);
            acc.z = fmaf(wgt[q].z * s, v[g][q].z, acc.z);
            acc.w = fmaf(wgt[q].w * s, v[g][q].w, acc.w);
        }
        o4[g * (256 * 256 / 4) + t] = acc;      // C = g*256 + cw
    }
}

extern "C" void kernel_launch(void* const* d_in, const int* in_sizes, int n_in,
                              void* d_out, int out_size, void* d_ws, size_t ws_size,
                              hipStream_t stream) {
    const float* input  = (const float*)d_in[0];   // [32,16,16,1024]
    const float* weight = (const float*)d_in[1];   // [32,256,9,256]
    float* out = (float*)d_out;                    // [32,1024,16,16]

    dim3 grid(32 * 64);    // (n, cw-block-of-4)
    dim3 block(256);       // 4 waves: one cw each
    hipLaunchKernelGGL(Aggregation_33320356282418_kernel, grid, block, 0, stream,
                       input, weight, out);
}